// Round 20
// baseline (122.266 us; speedup 1.0000x reference)
//
#include <hip/hip_runtime.h>
#include <math.h>

#define Bn 64
#define Sn 512
#define Hn 768
#define Mn 512
#define Tn 26
#define TP 32   // padded tag dim in global Eexp

// ws layout (float units)
#define OFF_BC    0                         // bc[32]
#define OFF_BFRAG 32                        // 24576 bf16 (short) = 12288 floats
#define OFF_EX    (32 + 12288)              // Eexp[b][s][32] f32
#define EXSZ      ((size_t)Bn*Sn*TP)        // 1048576
#define OFF_QG    (OFF_EX + EXSZ)           // Q bf16x2: [1024 tasks][16 pairs][32] u32
#define QGSZ      524288

typedef __attribute__((ext_vector_type(8)))  short bfrag;
typedef __attribute__((ext_vector_type(4)))  float f32x4;
typedef __attribute__((ext_vector_type(16))) float f32x16;

__device__ __forceinline__ short f2bf(float f) {   // RNE float->bf16 bits
    unsigned u = __float_as_uint(f);
    unsigned r = (u + 0x7FFFu + ((u >> 16) & 1u)) >> 16;
    return (short)r;
}
__device__ __forceinline__ unsigned cvtpk(float a, float b) {
    unsigned r;
    asm("v_cvt_pk_bf16_f32 %0, %1, %2" : "=v"(r) : "v"(a), "v"(b));
    return r;
}
__device__ __forceinline__ void pswap(unsigned &a, unsigned &b) {
    asm("v_permlane32_swap_b32 %0, %1" : "+v"(a), "+v"(b));
}
__device__ __forceinline__ bfrag mkfrag(unsigned a, unsigned b, unsigned c, unsigned d) {
    union { unsigned u[4]; bfrag v; } x;
    x.u[0] = a; x.u[1] = b; x.u[2] = c; x.u[3] = d;
    return x.v;
}
__device__ __forceinline__ float rl(float x, int i) {
    return __uint_as_float(__builtin_amdgcn_readlane(__float_as_uint(x), i));
}
__device__ __forceinline__ float rfl(float x) {
    return __uint_as_float(__builtin_amdgcn_readfirstlane(__float_as_uint(x)));
}

// ---------------- Kernel A: Bfrag = bf16(W2@W1) via MFMA; bc ----------------
__global__ __launch_bounds__(256) void k_prep(const float* __restrict__ W1,
                                              const float* __restrict__ b1,
                                              const float* __restrict__ W2,
                                              const float* __restrict__ b2,
                                              float* __restrict__ ws) {
    const int bx = blockIdx.x;
    const int tid = threadIdx.x;
    if (bx == 48) {
        if (tid < TP) {
            float bcv = 0.f;
            if (tid < Tn) {
                float a0 = 0.f, a1 = 0.f, a2 = 0.f, a3 = 0.f;
                const float4* w2 = reinterpret_cast<const float4*>(W2 + (size_t)tid * Mn);
                const float4* bb = reinterpret_cast<const float4*>(b1);
                for (int m = 0; m < Mn / 4; ++m) {
                    float4 w = w2[m], v = bb[m];
                    a0 = fmaf(w.x, v.x, a0); a1 = fmaf(w.y, v.y, a1);
                    a2 = fmaf(w.z, v.z, a2); a3 = fmaf(w.w, v.w, a3);
                }
                bcv = b2[tid] + (a0 + a1) + (a2 + a3);
            }
            ws[OFF_BC + tid] = bcv;
        }
        return;
    }

    __shared__ float mrg[3][64][8];
    const int lane = tid & 63;
    const int wv   = tid >> 6;              // K-quarter
    const int k0   = bx * 16;
    const int colA = lane & 15;
    const int mj   = ((lane >> 4) & 3) * 8;

    f32x4 acc0 = {0.f, 0.f, 0.f, 0.f}, acc1 = {0.f, 0.f, 0.f, 0.f};
    for (int mq = 0; mq < 4; ++mq) {
        const int m0 = wv * 128 + mq * 32;
        bfrag av, bv0, bv1;
#pragma unroll
        for (int j = 0; j < 8; ++j)
            av[j] = f2bf(W1[(size_t)(m0 + mj + j) * Hn + k0 + colA]);
        {
            const float* p = W2 + (size_t)(lane & 15) * Mn + m0 + mj;
            float4 x = *reinterpret_cast<const float4*>(p);
            float4 y = *reinterpret_cast<const float4*>(p + 4);
            bv0 = mkfrag(cvtpk(x.x, x.y), cvtpk(x.z, x.w), cvtpk(y.x, y.y), cvtpk(y.z, y.w));
        }
        {
            int c = 16 + (lane & 15);
            bfrag z = {};
            if (c < Tn) {
                const float* p = W2 + (size_t)c * Mn + m0 + mj;
                float4 x = *reinterpret_cast<const float4*>(p);
                float4 y = *reinterpret_cast<const float4*>(p + 4);
                z = mkfrag(cvtpk(x.x, x.y), cvtpk(x.z, x.w), cvtpk(y.x, y.y), cvtpk(y.z, y.w));
            }
            bv1 = z;
        }
        acc0 = __builtin_amdgcn_mfma_f32_16x16x32_bf16(av, bv0, acc0, 0, 0, 0);
        acc1 = __builtin_amdgcn_mfma_f32_16x16x32_bf16(av, bv1, acc1, 0, 0, 0);
    }

    if (wv > 0) {
#pragma unroll
        for (int i = 0; i < 4; ++i) {
            mrg[wv - 1][lane][i]     = acc0[i];
            mrg[wv - 1][lane][4 + i] = acc1[i];
        }
    }
    __syncthreads();
    if (wv == 0) {
        unsigned short* Bfo = (unsigned short*)(ws + OFF_BFRAG);
#pragma unroll
        for (int i = 0; i < 4; ++i) {
            float v0 = acc0[i] + mrg[0][lane][i]     + mrg[1][lane][i]     + mrg[2][lane][i];
            float v1 = acc1[i] + mrg[0][lane][4 + i] + mrg[1][lane][4 + i] + mrg[2][lane][4 + i];
            int k   = k0 + ((lane >> 4) & 3) * 4 + i;
            int ks2 = k >> 5;
            int fl  = ((k >> 3) & 3) * 16 + (lane & 15);
            Bfo[((size_t)(ks2 * 2 + 0) * 64 + fl) * 8 + (k & 7)] = (unsigned short)f2bf(v0);
            Bfo[((size_t)(ks2 * 2 + 1) * 64 + fl) * 8 + (k & 7)] = (unsigned short)f2bf(v1);
        }
    }
}

// ---------------- Kernel B: Eexp = exp(hidden @ Wc^T + bc) via bf16 MFMA (R6/R13-exact) ----------------
#define LOADK(KS, FA, FB, BV0, BV1)                                                        \
    {                                                                                      \
        const float* ap = abase + (KS) * 32;                                               \
        FA = *reinterpret_cast<const float4*>(ap);                                         \
        FB = *reinterpret_cast<const float4*>(ap + 4);                                     \
        BV0 = *reinterpret_cast<const bfrag*>(Bf + ((size_t)((KS) * 2 + 0) * 64 + l) * 8); \
        BV1 = *reinterpret_cast<const bfrag*>(Bf + ((size_t)((KS) * 2 + 1) * 64 + l) * 8); \
    }

__global__ __launch_bounds__(64, 2) void k_gemm(const float* __restrict__ hidden,
                                                const float* __restrict__ ws,
                                                float* __restrict__ Eexp) {
    const int l    = threadIdx.x;
    const int row0 = blockIdx.x * 16;
    const int arow = row0 + (l & 15);
    const int kg   = l >> 4;                   // 0..3
    const float* abase = hidden + (size_t)arow * Hn + kg * 8;
    const unsigned short* Bf = (const unsigned short*)(ws + OFF_BFRAG);

    f32x4 acc0 = {0.f, 0.f, 0.f, 0.f}, acc1 = {0.f, 0.f, 0.f, 0.f};

    float4 fa0, fb0, fa1, fb1;
    bfrag bv00, bv01, bv10, bv11;
    LOADK(0, fa0, fb0, bv00, bv01);
    LOADK(1, fa1, fb1, bv10, bv11);

#pragma unroll 1
    for (int ks = 0; ks < 22; ks += 2) {
        float4 ta, tb; bfrag t0, t1;
        LOADK(ks + 2, ta, tb, t0, t1);
        bfrag av = mkfrag(cvtpk(fa0.x, fa0.y), cvtpk(fa0.z, fa0.w),
                          cvtpk(fb0.x, fb0.y), cvtpk(fb0.z, fb0.w));
        acc0 = __builtin_amdgcn_mfma_f32_16x16x32_bf16(av, bv00, acc0, 0, 0, 0);
        acc1 = __builtin_amdgcn_mfma_f32_16x16x32_bf16(av, bv01, acc1, 0, 0, 0);
        fa0 = ta; fb0 = tb; bv00 = t0; bv01 = t1;

        float4 ua, ub; bfrag u0, u1;
        LOADK(ks + 3, ua, ub, u0, u1);
        av = mkfrag(cvtpk(fa1.x, fa1.y), cvtpk(fa1.z, fa1.w),
                    cvtpk(fb1.x, fb1.y), cvtpk(fb1.z, fb1.w));
        acc0 = __builtin_amdgcn_mfma_f32_16x16x32_bf16(av, bv10, acc0, 0, 0, 0);
        acc1 = __builtin_amdgcn_mfma_f32_16x16x32_bf16(av, bv11, acc1, 0, 0, 0);
        fa1 = ua; fb1 = ub; bv10 = u0; bv11 = u1;
    }
    {
        bfrag av = mkfrag(cvtpk(fa0.x, fa0.y), cvtpk(fa0.z, fa0.w),
                          cvtpk(fb0.x, fb0.y), cvtpk(fb0.z, fb0.w));
        acc0 = __builtin_amdgcn_mfma_f32_16x16x32_bf16(av, bv00, acc0, 0, 0, 0);
        acc1 = __builtin_amdgcn_mfma_f32_16x16x32_bf16(av, bv01, acc1, 0, 0, 0);
        av = mkfrag(cvtpk(fa1.x, fa1.y), cvtpk(fa1.z, fa1.w),
                    cvtpk(fb1.x, fb1.y), cvtpk(fb1.z, fb1.w));
        acc0 = __builtin_amdgcn_mfma_f32_16x16x32_bf16(av, bv10, acc0, 0, 0, 0);
        acc1 = __builtin_amdgcn_mfma_f32_16x16x32_bf16(av, bv11, acc1, 0, 0, 0);
    }

    const int c0 = l & 15;
    const int rbase = row0 + kg * 4;
    float bc0 = ws[OFF_BC + c0], bc1 = ws[OFF_BC + 16 + c0];
#pragma unroll
    for (int i = 0; i < 4; ++i) {
        Eexp[(size_t)(rbase + i) * TP + c0]      = __expf(acc0[i] + bc0);
        Eexp[(size_t)(rbase + i) * TP + 16 + c0] = __expf(acc1[i] + bc1);
    }
}

// ---------------- Kernel C1: chunk Q products, all 256 CUs (R13-exact) ----------------
__global__ __launch_bounds__(256) void k_chunk(const float* __restrict__ Eexp,
                                               const float* __restrict__ trans,
                                               const int* __restrict__ lengths,
                                               unsigned* __restrict__ Qg) {
    __shared__ float Ech[4][32][32];      // 16 KB, one slice per wave
    const int tid  = threadIdx.x;
    const int wv   = tid >> 6;
    const int lane = tid & 63;
    const int task = blockIdx.x * 4 + wv;
    const int b    = task >> 4;
    const int c    = task & 15;
    const int len  = lengths[b];
    const int s0   = c * 32;
    int nact = len - 1 - s0;
    nact = nact < 0 ? 0 : (nact > 32 ? 32 : nact);
    const int t = lane & 31;
    const int h = lane >> 5;

    {
        const float* Eb = Eexp + (size_t)b * Sn * TP;
        int lr = lane >> 1, hf = lane & 1;
        int s = s0 + 1 + lr; s = s > 511 ? 511 : s;
        const float4* src = reinterpret_cast<const float4*>(Eb + (size_t)s * TP + hf * 16);
        float4* dst = reinterpret_cast<float4*>(&Ech[wv][lr][hf * 16]);
        dst[0] = src[0]; dst[1] = src[1]; dst[2] = src[2]; dst[3] = src[3];
    }

    bfrag A0, A1, B0, B1;
#pragma unroll
    for (int j = 0; j < 8; ++j) {
        int k0 = 8 * h + j, k1 = 16 + 8 * h + j;
        A0[j] = (t < Tn && k0 < Tn) ? f2bf(__expf(trans[k0 * Tn + t]) * 0.03125f) : (short)0;
        A1[j] = (t < Tn && k1 < Tn) ? f2bf(__expf(trans[k1 * Tn + t]) * 0.03125f) : (short)0;
        B0[j] = (k0 == t) ? (short)0x3F80 : (short)0;
        B1[j] = (k1 == t) ? (short)0x3F80 : (short)0;
    }

    float qf[16];
#pragma unroll
    for (int r = 0; r < 16; ++r) {
        int row = (r & 3) + 8 * (r >> 2) + 4 * h;
        qf[r] = (row == t) ? 1.f : 0.f;
    }

    for (int j = 0; j < nact; ++j) {
        f32x16 acc = {};
        acc = __builtin_amdgcn_mfma_f32_32x32x16_bf16(A0, B0, acc, 0, 0, 0);
        acc = __builtin_amdgcn_mfma_f32_32x32x16_bf16(A1, B1, acc, 0, 0, 0);
        const float* ep = &Ech[wv][j][4 * h];
        float4 e0 = *reinterpret_cast<const float4*>(ep);
        float4 e1 = *reinterpret_cast<const float4*>(ep + 8);
        float4 e2 = *reinterpret_cast<const float4*>(ep + 16);
        float4 e3 = *reinterpret_cast<const float4*>(ep + 24);
        float ev[16];
        ev[0]  = e0.x; ev[1]  = e0.y; ev[2]  = e0.z; ev[3]  = e0.w;
        ev[4]  = e1.x; ev[5]  = e1.y; ev[6]  = e1.z; ev[7]  = e1.w;
        ev[8]  = e2.x; ev[9]  = e2.y; ev[10] = e2.z; ev[11] = e2.w;
        ev[12] = e3.x; ev[13] = e3.y; ev[14] = e3.z; ev[15] = e3.w;
#pragma unroll
        for (int r = 0; r < 16; ++r) qf[r] = acc[r] * ev[r];
        if (j + 1 < nact) {
            unsigned W0 = cvtpk(qf[0],  qf[1]),  W1 = cvtpk(qf[2],  qf[3]);
            unsigned W2 = cvtpk(qf[4],  qf[5]),  W3 = cvtpk(qf[6],  qf[7]);
            unsigned W4 = cvtpk(qf[8],  qf[9]),  W5 = cvtpk(qf[10], qf[11]);
            unsigned W6 = cvtpk(qf[12], qf[13]), W7 = cvtpk(qf[14], qf[15]);
            pswap(W0, W2); pswap(W1, W3); pswap(W4, W6); pswap(W5, W7);
            B0 = mkfrag(W0, W1, W2, W3);
            B1 = mkfrag(W4, W5, W6, W7);
        }
    }

    unsigned* qdst = Qg + (size_t)task * 512;
#pragma unroll
    for (int g = 0; g < 4; ++g) {
        unsigned u0 = cvtpk(qf[4*g + 0], qf[4*g + 1]);
        unsigned u1 = cvtpk(qf[4*g + 2], qf[4*g + 3]);
        qdst[(4*g + 2*h)     * 32 + t] = u0;
        qdst[(4*g + 2*h + 1) * 32 + t] = u1;
    }
}

// ---------------- Kernel C2: single-block combine + numerator + mean (NO atomics) ----------------
// 1 block x 1024 threads (16 waves). Wave w handles batches 4w..4w+3 serially:
// denominator (R13's prefetched chain) then numerator (8-iter predicated unroll).
// llh to LDS; wave 0 reduces and writes out.
__global__ __launch_bounds__(1024, 1) void k_comb1(const float* __restrict__ Eexp,
                                                   const unsigned* __restrict__ Qg,
                                                   const float* __restrict__ start_t,
                                                   const float* __restrict__ end_t,
                                                   const float* __restrict__ trans,
                                                   const int* __restrict__ labels,
                                                   const int* __restrict__ lengths,
                                                   float* __restrict__ out) {
    __shared__ float llhs[64];
    const int tid  = threadIdx.x;
    const int wv   = tid >> 6;
    const int lane = tid & 63;
    const int t    = lane & 31;

#pragma unroll 1
    for (int qb = 0; qb < 4; ++qb) {
        const int b   = wv * 4 + qb;
        const int len = lengths[b];

        // ---- denominator: alpha through 16 chunk matrices (2-deep prefetch) ----
        float alpha = (t < Tn) ? __expf(start_t[t]) * Eexp[(size_t)b * Sn * TP + t] : 0.f;
        float logZ = 0.f;
        const unsigned* Qb = Qg + (size_t)b * 16 * 512 + t;
        unsigned q0[16], q1[16];
#pragma unroll
        for (int p = 0; p < 16; ++p) q0[p] = Qb[p * 32];
        for (int c = 0; c < 16; ++c) {
            int cn = c < 15 ? c + 1 : 15;
#pragma unroll
            for (int p = 0; p < 16; ++p) q1[p] = Qb[(size_t)cn * 512 + p * 32];
            float p0 = 0.f, p1 = 0.f, p2 = 0.f, p3 = 0.f;
#pragma unroll
            for (int p = 0; p < 16; p += 2) {
                unsigned ua = q0[p];
                unsigned ub = q0[p + 1];
                p0 = fmaf(rl(alpha, 2*p    ), __uint_as_float(ua << 16),          p0);
                p1 = fmaf(rl(alpha, 2*p + 1), __uint_as_float(ua & 0xFFFF0000u), p1);
                p2 = fmaf(rl(alpha, 2*p + 2), __uint_as_float(ub << 16),          p2);
                p3 = fmaf(rl(alpha, 2*p + 3), __uint_as_float(ub & 0xFFFF0000u), p3);
            }
            float v = (p0 + p1) + (p2 + p3);
            float C = rfl(v);
            alpha = v / C;
            logZ += __logf(C);
#pragma unroll
            for (int p = 0; p < 16; ++p) q0[p] = q1[p];
        }
        float dv = (t < Tn && lane < 32) ? alpha * __expf(end_t[t]) : 0.f;
#pragma unroll
        for (int off = 32; off; off >>= 1) dv += __shfl_xor(dv, off);

        // ---- numerator: 8-iter predicated unroll (all loads issued up front) ----
        const int base = b * Sn;
        float part = 0.f;
#pragma unroll
        for (int k = 0; k < 8; ++k) {
            int s2 = 1 + lane + k * 64;
            bool valid = s2 < len;
            int s2c = valid ? s2 : 1;
            int lp = labels[base + s2c - 1];
            int lc = labels[base + s2c];
            float vv = trans[lp * Tn + lc]
                     + __logf(Eexp[(size_t)(base + s2c) * TP + lc]);
            part += valid ? vv : 0.f;
        }
#pragma unroll
        for (int off = 32; off; off >>= 1) part += __shfl_xor(part, off);

        if (lane == 0) {
            int l0 = labels[base], ll = labels[base + len - 1];
            float numer = part + start_t[l0] + __logf(Eexp[(size_t)base * TP + l0]) + end_t[ll];
            float denom = logZ + __logf(dv) + (float)(len - 1) * 3.46573590279973f;
            llhs[b] = numer - denom;
        }
    }
    __syncthreads();

    if (wv == 0) {
        float v = llhs[lane];
#pragma unroll
        for (int off = 32; off; off >>= 1) v += __shfl_xor(v, off);
        if (lane == 0) out[0] = -v * (1.0f / 64.0f);
    }
}

extern "C" void kernel_launch(void* const* d_in, const int* in_sizes, int n_in,
                              void* d_out, int out_size, void* d_ws, size_t ws_size,
                              hipStream_t stream) {
    const float* hidden  = (const float*)d_in[0];
    const float* W1      = (const float*)d_in[1];
    const float* b1      = (const float*)d_in[2];
    const float* W2      = (const float*)d_in[3];
    const float* b2      = (const float*)d_in[4];
    const float* start_t = (const float*)d_in[5];
    const float* end_t   = (const float*)d_in[6];
    const float* trans   = (const float*)d_in[7];
    const int*   labels  = (const int*)d_in[8];
    const int*   lengths = (const int*)d_in[9];
    float* ws  = (float*)d_ws;
    float* out = (float*)d_out;

    hipLaunchKernelGGL(k_prep, dim3(49), dim3(256), 0, stream, W1, b1, W2, b2, ws);
    hipLaunchKernelGGL(k_gemm, dim3(2048), dim3(64), 0, stream, hidden, ws, ws + OFF_EX);
    hipLaunchKernelGGL(k_chunk, dim3(256), dim3(256), 0, stream, ws + OFF_EX, trans,
                       lengths, (unsigned*)(ws + OFF_QG));
    hipLaunchKernelGGL(k_comb1, dim3(1), dim3(1024), 0, stream, ws + OFF_EX,
                       (const unsigned*)(ws + OFF_QG), start_t, end_t, trans, labels,
                       lengths, out);
}

// Round 21
// 51.446 us; speedup vs baseline: 2.3766x; 2.3766x over previous
//
#include <hip/hip_runtime.h>
#include <math.h>

#define Bn 64
#define Sn 512
#define Hn 768
#define Mn 512
#define Tn 26
#define TP 32   // padded tag dim in global Eexp

// ws layout (float units)
#define OFF_BC    0                         // bc[32]
#define OFF_BFRAG 32                        // 24576 bf16 (short) = 12288 floats
#define OFF_EX    (32 + 12288)              // Eexp[b][s][32] f32
#define EXSZ      ((size_t)Bn*Sn*TP)        // 1048576
#define OFF_QG    (OFF_EX + EXSZ)           // Q bf16x2: [1024 tasks][16 pairs][32] u32
#define QGSZ      524288
#define OFF_LLH   (OFF_QG + QGSZ)           // llh[64]

typedef __attribute__((ext_vector_type(8)))  short bfrag;
typedef __attribute__((ext_vector_type(4)))  float f32x4;
typedef __attribute__((ext_vector_type(16))) float f32x16;

__device__ __forceinline__ short f2bf(float f) {   // RNE float->bf16 bits
    unsigned u = __float_as_uint(f);
    unsigned r = (u + 0x7FFFu + ((u >> 16) & 1u)) >> 16;
    return (short)r;
}
__device__ __forceinline__ unsigned cvtpk(float a, float b) {
    unsigned r;
    asm("v_cvt_pk_bf16_f32 %0, %1, %2" : "=v"(r) : "v"(a), "v"(b));
    return r;
}
__device__ __forceinline__ void pswap(unsigned &a, unsigned &b) {
    asm("v_permlane32_swap_b32 %0, %1" : "+v"(a), "+v"(b));
}
__device__ __forceinline__ bfrag mkfrag(unsigned a, unsigned b, unsigned c, unsigned d) {
    union { unsigned u[4]; bfrag v; } x;
    x.u[0] = a; x.u[1] = b; x.u[2] = c; x.u[3] = d;
    return x.v;
}
__device__ __forceinline__ float rl(float x, int i) {
    return __uint_as_float(__builtin_amdgcn_readlane(__float_as_uint(x), i));
}
__device__ __forceinline__ float rfl(float x) {
    return __uint_as_float(__builtin_amdgcn_readfirstlane(__float_as_uint(x)));
}

// ---------------- Kernel A: Bfrag = bf16(W2@W1) via MFMA; bc ----------------
__global__ __launch_bounds__(256) void k_prep(const float* __restrict__ W1,
                                              const float* __restrict__ b1,
                                              const float* __restrict__ W2,
                                              const float* __restrict__ b2,
                                              float* __restrict__ ws) {
    const int bx = blockIdx.x;
    const int tid = threadIdx.x;
    if (bx == 48) {
        if (tid < TP) {
            float bcv = 0.f;
            if (tid < Tn) {
                float a0 = 0.f, a1 = 0.f, a2 = 0.f, a3 = 0.f;
                const float4* w2 = reinterpret_cast<const float4*>(W2 + (size_t)tid * Mn);
                const float4* bb = reinterpret_cast<const float4*>(b1);
                for (int m = 0; m < Mn / 4; ++m) {
                    float4 w = w2[m], v = bb[m];
                    a0 = fmaf(w.x, v.x, a0); a1 = fmaf(w.y, v.y, a1);
                    a2 = fmaf(w.z, v.z, a2); a3 = fmaf(w.w, v.w, a3);
                }
                bcv = b2[tid] + (a0 + a1) + (a2 + a3);
            }
            ws[OFF_BC + tid] = bcv;
        }
        return;
    }

    __shared__ float mrg[3][64][8];
    const int lane = tid & 63;
    const int wv   = tid >> 6;              // K-quarter
    const int k0   = bx * 16;
    const int colA = lane & 15;
    const int mj   = ((lane >> 4) & 3) * 8;

    f32x4 acc0 = {0.f, 0.f, 0.f, 0.f}, acc1 = {0.f, 0.f, 0.f, 0.f};
    for (int mq = 0; mq < 4; ++mq) {
        const int m0 = wv * 128 + mq * 32;
        bfrag av, bv0, bv1;
#pragma unroll
        for (int j = 0; j < 8; ++j)
            av[j] = f2bf(W1[(size_t)(m0 + mj + j) * Hn + k0 + colA]);
        {
            const float* p = W2 + (size_t)(lane & 15) * Mn + m0 + mj;
            float4 x = *reinterpret_cast<const float4*>(p);
            float4 y = *reinterpret_cast<const float4*>(p + 4);
            bv0 = mkfrag(cvtpk(x.x, x.y), cvtpk(x.z, x.w), cvtpk(y.x, y.y), cvtpk(y.z, y.w));
        }
        {
            int c = 16 + (lane & 15);
            bfrag z = {};
            if (c < Tn) {
                const float* p = W2 + (size_t)c * Mn + m0 + mj;
                float4 x = *reinterpret_cast<const float4*>(p);
                float4 y = *reinterpret_cast<const float4*>(p + 4);
                z = mkfrag(cvtpk(x.x, x.y), cvtpk(x.z, x.w), cvtpk(y.x, y.y), cvtpk(y.z, y.w));
            }
            bv1 = z;
        }
        acc0 = __builtin_amdgcn_mfma_f32_16x16x32_bf16(av, bv0, acc0, 0, 0, 0);
        acc1 = __builtin_amdgcn_mfma_f32_16x16x32_bf16(av, bv1, acc1, 0, 0, 0);
    }

    if (wv > 0) {
#pragma unroll
        for (int i = 0; i < 4; ++i) {
            mrg[wv - 1][lane][i]     = acc0[i];
            mrg[wv - 1][lane][4 + i] = acc1[i];
        }
    }
    __syncthreads();
    if (wv == 0) {
        unsigned short* Bfo = (unsigned short*)(ws + OFF_BFRAG);
#pragma unroll
        for (int i = 0; i < 4; ++i) {
            float v0 = acc0[i] + mrg[0][lane][i]     + mrg[1][lane][i]     + mrg[2][lane][i];
            float v1 = acc1[i] + mrg[0][lane][4 + i] + mrg[1][lane][4 + i] + mrg[2][lane][4 + i];
            int k   = k0 + ((lane >> 4) & 3) * 4 + i;
            int ks2 = k >> 5;
            int fl  = ((k >> 3) & 3) * 16 + (lane & 15);
            Bfo[((size_t)(ks2 * 2 + 0) * 64 + fl) * 8 + (k & 7)] = (unsigned short)f2bf(v0);
            Bfo[((size_t)(ks2 * 2 + 1) * 64 + fl) * 8 + (k & 7)] = (unsigned short)f2bf(v1);
        }
    }
}

// ---------------- Kernel B: Eexp = exp(hidden @ Wc^T + bc) via bf16 MFMA (R6/R13-exact) ----------------
#define LOADK(KS, FA, FB, BV0, BV1)                                                        \
    {                                                                                      \
        const float* ap = abase + (KS) * 32;                                               \
        FA = *reinterpret_cast<const float4*>(ap);                                         \
        FB = *reinterpret_cast<const float4*>(ap + 4);                                     \
        BV0 = *reinterpret_cast<const bfrag*>(Bf + ((size_t)((KS) * 2 + 0) * 64 + l) * 8); \
        BV1 = *reinterpret_cast<const bfrag*>(Bf + ((size_t)((KS) * 2 + 1) * 64 + l) * 8); \
    }

__global__ __launch_bounds__(64, 2) void k_gemm(const float* __restrict__ hidden,
                                                const float* __restrict__ ws,
                                                float* __restrict__ Eexp) {
    const int l    = threadIdx.x;
    const int row0 = blockIdx.x * 16;
    const int arow = row0 + (l & 15);
    const int kg   = l >> 4;                   // 0..3
    const float* abase = hidden + (size_t)arow * Hn + kg * 8;
    const unsigned short* Bf = (const unsigned short*)(ws + OFF_BFRAG);

    f32x4 acc0 = {0.f, 0.f, 0.f, 0.f}, acc1 = {0.f, 0.f, 0.f, 0.f};

    float4 fa0, fb0, fa1, fb1;
    bfrag bv00, bv01, bv10, bv11;
    LOADK(0, fa0, fb0, bv00, bv01);
    LOADK(1, fa1, fb1, bv10, bv11);

#pragma unroll 1
    for (int ks = 0; ks < 22; ks += 2) {
        float4 ta, tb; bfrag t0, t1;
        LOADK(ks + 2, ta, tb, t0, t1);
        bfrag av = mkfrag(cvtpk(fa0.x, fa0.y), cvtpk(fa0.z, fa0.w),
                          cvtpk(fb0.x, fb0.y), cvtpk(fb0.z, fb0.w));
        acc0 = __builtin_amdgcn_mfma_f32_16x16x32_bf16(av, bv00, acc0, 0, 0, 0);
        acc1 = __builtin_amdgcn_mfma_f32_16x16x32_bf16(av, bv01, acc1, 0, 0, 0);
        fa0 = ta; fb0 = tb; bv00 = t0; bv01 = t1;

        float4 ua, ub; bfrag u0, u1;
        LOADK(ks + 3, ua, ub, u0, u1);
        av = mkfrag(cvtpk(fa1.x, fa1.y), cvtpk(fa1.z, fa1.w),
                    cvtpk(fb1.x, fb1.y), cvtpk(fb1.z, fb1.w));
        acc0 = __builtin_amdgcn_mfma_f32_16x16x32_bf16(av, bv10, acc0, 0, 0, 0);
        acc1 = __builtin_amdgcn_mfma_f32_16x16x32_bf16(av, bv11, acc1, 0, 0, 0);
        fa1 = ua; fb1 = ub; bv10 = u0; bv11 = u1;
    }
    {
        bfrag av = mkfrag(cvtpk(fa0.x, fa0.y), cvtpk(fa0.z, fa0.w),
                          cvtpk(fb0.x, fb0.y), cvtpk(fb0.z, fb0.w));
        acc0 = __builtin_amdgcn_mfma_f32_16x16x32_bf16(av, bv00, acc0, 0, 0, 0);
        acc1 = __builtin_amdgcn_mfma_f32_16x16x32_bf16(av, bv01, acc1, 0, 0, 0);
        av = mkfrag(cvtpk(fa1.x, fa1.y), cvtpk(fa1.z, fa1.w),
                    cvtpk(fb1.x, fb1.y), cvtpk(fb1.z, fb1.w));
        acc0 = __builtin_amdgcn_mfma_f32_16x16x32_bf16(av, bv10, acc0, 0, 0, 0);
        acc1 = __builtin_amdgcn_mfma_f32_16x16x32_bf16(av, bv11, acc1, 0, 0, 0);
    }

    const int c0 = l & 15;
    const int rbase = row0 + kg * 4;
    float bc0 = ws[OFF_BC + c0], bc1 = ws[OFF_BC + 16 + c0];
#pragma unroll
    for (int i = 0; i < 4; ++i) {
        Eexp[(size_t)(rbase + i) * TP + c0]      = __expf(acc0[i] + bc0);
        Eexp[(size_t)(rbase + i) * TP + 16 + c0] = __expf(acc1[i] + bc1);
    }
}

// ---------------- Kernel C1: chunk Q products, all 256 CUs (R13-exact) ----------------
__global__ __launch_bounds__(256) void k_chunk(const float* __restrict__ Eexp,
                                               const float* __restrict__ trans,
                                               const int* __restrict__ lengths,
                                               unsigned* __restrict__ Qg) {
    __shared__ float Ech[4][32][32];      // 16 KB, one slice per wave
    const int tid  = threadIdx.x;
    const int wv   = tid >> 6;
    const int lane = tid & 63;
    const int task = blockIdx.x * 4 + wv;
    const int b    = task >> 4;
    const int c    = task & 15;
    const int len  = lengths[b];
    const int s0   = c * 32;
    int nact = len - 1 - s0;
    nact = nact < 0 ? 0 : (nact > 32 ? 32 : nact);
    const int t = lane & 31;
    const int h = lane >> 5;

    {
        const float* Eb = Eexp + (size_t)b * Sn * TP;
        int lr = lane >> 1, hf = lane & 1;
        int s = s0 + 1 + lr; s = s > 511 ? 511 : s;
        const float4* src = reinterpret_cast<const float4*>(Eb + (size_t)s * TP + hf * 16);
        float4* dst = reinterpret_cast<float4*>(&Ech[wv][lr][hf * 16]);
        dst[0] = src[0]; dst[1] = src[1]; dst[2] = src[2]; dst[3] = src[3];
    }

    bfrag A0, A1, B0, B1;
#pragma unroll
    for (int j = 0; j < 8; ++j) {
        int k0 = 8 * h + j, k1 = 16 + 8 * h + j;
        A0[j] = (t < Tn && k0 < Tn) ? f2bf(__expf(trans[k0 * Tn + t]) * 0.03125f) : (short)0;
        A1[j] = (t < Tn && k1 < Tn) ? f2bf(__expf(trans[k1 * Tn + t]) * 0.03125f) : (short)0;
        B0[j] = (k0 == t) ? (short)0x3F80 : (short)0;
        B1[j] = (k1 == t) ? (short)0x3F80 : (short)0;
    }

    float qf[16];
#pragma unroll
    for (int r = 0; r < 16; ++r) {
        int row = (r & 3) + 8 * (r >> 2) + 4 * h;
        qf[r] = (row == t) ? 1.f : 0.f;
    }

    for (int j = 0; j < nact; ++j) {
        f32x16 acc = {};
        acc = __builtin_amdgcn_mfma_f32_32x32x16_bf16(A0, B0, acc, 0, 0, 0);
        acc = __builtin_amdgcn_mfma_f32_32x32x16_bf16(A1, B1, acc, 0, 0, 0);
        const float* ep = &Ech[wv][j][4 * h];
        float4 e0 = *reinterpret_cast<const float4*>(ep);
        float4 e1 = *reinterpret_cast<const float4*>(ep + 8);
        float4 e2 = *reinterpret_cast<const float4*>(ep + 16);
        float4 e3 = *reinterpret_cast<const float4*>(ep + 24);
        float ev[16];
        ev[0]  = e0.x; ev[1]  = e0.y; ev[2]  = e0.z; ev[3]  = e0.w;
        ev[4]  = e1.x; ev[5]  = e1.y; ev[6]  = e1.z; ev[7]  = e1.w;
        ev[8]  = e2.x; ev[9]  = e2.y; ev[10] = e2.z; ev[11] = e2.w;
        ev[12] = e3.x; ev[13] = e3.y; ev[14] = e3.z; ev[15] = e3.w;
#pragma unroll
        for (int r = 0; r < 16; ++r) qf[r] = acc[r] * ev[r];
        if (j + 1 < nact) {
            unsigned W0 = cvtpk(qf[0],  qf[1]),  W1 = cvtpk(qf[2],  qf[3]);
            unsigned W2 = cvtpk(qf[4],  qf[5]),  W3 = cvtpk(qf[6],  qf[7]);
            unsigned W4 = cvtpk(qf[8],  qf[9]),  W5 = cvtpk(qf[10], qf[11]);
            unsigned W6 = cvtpk(qf[12], qf[13]), W7 = cvtpk(qf[14], qf[15]);
            pswap(W0, W2); pswap(W1, W3); pswap(W4, W6); pswap(W5, W7);
            B0 = mkfrag(W0, W1, W2, W3);
            B1 = mkfrag(W4, W5, W6, W7);
        }
    }

    unsigned* qdst = Qg + (size_t)task * 512;
#pragma unroll
    for (int g = 0; g < 4; ++g) {
        unsigned u0 = cvtpk(qf[4*g + 0], qf[4*g + 1]);
        unsigned u1 = cvtpk(qf[4*g + 2], qf[4*g + 3]);
        qdst[(4*g + 2*h)     * 32 + t] = u0;
        qdst[(4*g + 2*h + 1) * 32 + t] = u1;
    }
}

// ---------------- Kernel C2: combine + numerator -> llh[b] (NO atomics, NO fences) ----------------
__global__ __launch_bounds__(128) void k_comb(const float* __restrict__ Eexp,
                                              const unsigned* __restrict__ Qg,
                                              const float* __restrict__ start_t,
                                              const float* __restrict__ end_t,
                                              const float* __restrict__ trans,
                                              const int* __restrict__ labels,
                                              const int* __restrict__ lengths,
                                              float* __restrict__ llh) {
    __shared__ float comm[2];
    const int tid  = threadIdx.x;
    const int b    = blockIdx.x;
    const int len  = lengths[b];
    const int wv   = tid >> 6;
    const int lane = tid & 63;

    if (wv == 0) {
        const int t = lane & 31;
        float alpha = (t < Tn) ? __expf(start_t[t]) * Eexp[(size_t)b * Sn * TP + t] : 0.f;
        float logZ = 0.f;
        const unsigned* Qb = Qg + (size_t)b * 16 * 512 + t;
        unsigned q0[16], q1[16];
#pragma unroll
        for (int p = 0; p < 16; ++p) q0[p] = Qb[p * 32];
        for (int c = 0; c < 16; ++c) {
            int cn = c < 15 ? c + 1 : 15;
#pragma unroll
            for (int p = 0; p < 16; ++p) q1[p] = Qb[(size_t)cn * 512 + p * 32];
            float p0 = 0.f, p1 = 0.f, p2 = 0.f, p3 = 0.f;
#pragma unroll
            for (int p = 0; p < 16; p += 2) {
                unsigned ua = q0[p];
                unsigned ub = q0[p + 1];
                p0 = fmaf(rl(alpha, 2*p    ), __uint_as_float(ua << 16),          p0);
                p1 = fmaf(rl(alpha, 2*p + 1), __uint_as_float(ua & 0xFFFF0000u), p1);
                p2 = fmaf(rl(alpha, 2*p + 2), __uint_as_float(ub << 16),          p2);
                p3 = fmaf(rl(alpha, 2*p + 3), __uint_as_float(ub & 0xFFFF0000u), p3);
            }
            float v = (p0 + p1) + (p2 + p3);
            float C = rfl(v);
            alpha = v / C;
            logZ += __logf(C);
#pragma unroll
            for (int p = 0; p < 16; ++p) q0[p] = q1[p];
        }
        float dv = (lane < 32 && t < Tn) ? alpha * __expf(end_t[t]) : 0.f;
#pragma unroll
        for (int off = 32; off; off >>= 1) dv += __shfl_xor(dv, off);
        if (lane == 0)
            comm[0] = logZ + __logf(dv) + (float)(len - 1) * 3.46573590279973f;
    } else {
        const int base = b * Sn;
        const float* Eb2 = Eexp + (size_t)base * TP;
        float part = 0.f;
        for (int s2 = 1 + lane; s2 < len; s2 += 64) {
            int lp = labels[base + s2 - 1];
            int lc = labels[base + s2];
            part += trans[lp * Tn + lc] + __logf(Eb2[(size_t)s2 * TP + lc]);
        }
#pragma unroll
        for (int off = 32; off; off >>= 1) part += __shfl_xor(part, off);
        if (lane == 0) {
            int l0 = labels[base], ll = labels[base + len - 1];
            comm[1] = part + start_t[l0] + __logf(Eb2[l0]) + end_t[ll];
        }
    }
    __syncthreads();
    if (tid == 0) llh[b] = comm[1] - comm[0];
}

// ---------------- Kernel D: out = -mean(llh) ----------------
__global__ __launch_bounds__(64) void k_final(const float* __restrict__ llh,
                                              float* __restrict__ out) {
    float v = llh[threadIdx.x];
#pragma unroll
    for (int off = 32; off; off >>= 1) v += __shfl_xor(v, off);
    if (threadIdx.x == 0) out[0] = -v * (1.0f / 64.0f);
}

extern "C" void kernel_launch(void* const* d_in, const int* in_sizes, int n_in,
                              void* d_out, int out_size, void* d_ws, size_t ws_size,
                              hipStream_t stream) {
    const float* hidden  = (const float*)d_in[0];
    const float* W1      = (const float*)d_in[1];
    const float* b1      = (const float*)d_in[2];
    const float* W2      = (const float*)d_in[3];
    const float* b2      = (const float*)d_in[4];
    const float* start_t = (const float*)d_in[5];
    const float* end_t   = (const float*)d_in[6];
    const float* trans   = (const float*)d_in[7];
    const int*   labels  = (const int*)d_in[8];
    const int*   lengths = (const int*)d_in[9];
    float* ws  = (float*)d_ws;
    float* out = (float*)d_out;

    hipLaunchKernelGGL(k_prep, dim3(49), dim3(256), 0, stream, W1, b1, W2, b2, ws);
    hipLaunchKernelGGL(k_gemm, dim3(2048), dim3(64), 0, stream, hidden, ws, ws + OFF_EX);
    hipLaunchKernelGGL(k_chunk, dim3(256), dim3(256), 0, stream, ws + OFF_EX, trans,
                       lengths, (unsigned*)(ws + OFF_QG));
    hipLaunchKernelGGL(k_comb, dim3(64), dim3(128), 0, stream, ws + OFF_EX,
                       (const unsigned*)(ws + OFF_QG), start_t, end_t, trans, labels,
                       lengths, ws + OFF_LLH);
    hipLaunchKernelGGL(k_final, dim3(1), dim3(64), 0, stream, ws + OFF_LLH, out);
}